// Round 17
// baseline (566.821 us; speedup 1.0000x reference)
//
#include <hip/hip_runtime.h>
#include <hip/hip_bf16.h>
#include <stdint.h>

typedef __attribute__((ext_vector_type(8))) short bf16x8;
typedef __attribute__((ext_vector_type(4))) float f32x4;

// Contraction-proof single f32 ops (np emulation must stay unfused).
__device__ __forceinline__ float vmulf(float a, float b) {
    float d; asm volatile("v_mul_f32 %0, %1, %2" : "=v"(d) : "v"(a), "v"(b)); return d;
}
__device__ __forceinline__ float vaddf(float a, float b) {
    float d; asm volatile("v_add_f32 %0, %1, %2" : "=v"(d) : "v"(a), "v"(b)); return d;
}
__device__ __forceinline__ float vsubf(float a, float b) {
    float d; asm volatile("v_sub_f32 %0, %1, %2" : "=v"(d) : "v"(a), "v"(b)); return d;
}

__device__ __forceinline__ short bf16h(float v) {
    __hip_bfloat16 h = __float2bfloat16(v);
    return *(short*)&h;
}
__device__ __forceinline__ float bf16f(short s) {
    return __uint_as_float(((unsigned int)(unsigned short)s) << 16);
}
__device__ __forceinline__ void split2(float v, short& h, short& m) {
    h = bf16h(v);
    m = bf16h(__fsub_rn(v, bf16f(h)));
}

__device__ __forceinline__ float decode_scalar(const void* p, float dflt) {
    float f = *(const float*)p;
    if (!(f == f) || fabsf(f) > 1.0e6f) return dflt;
    return f;
}
__device__ __forceinline__ int decode_ts(const void* p) {
    int w = *(const int*)p;
    if (w >= 1 && w <= 100000) return w;
    return 32;
}

// ---------------- k1: bit-exact emulation of np-f32 pipeline ----------------
// CLEAN chain ledger (asm-unfused scan, valid tests): MFMA-f32acc x (R4),
// f64 end-to-end x (R5), OpenBLAS-Zen [384,320,320] x (R10), OpenBLAS-
// SkylakeX [320,320,192,192] x (R11), single FMA chain x (R12, also kills
// skylakex sgemm_direct + AVX2 no-BLAS numpy), uniform [256x4] x (R13,
// BLIS-haswell/zen1), single mul+add x (R14, SSE2 no-BLAS), [384,384,256] x
// (R15, oneDNN-class), f64-matmul->f32-cast V1 x (R16).
// R17 hypothesis: AMD-stack host numpy linked against AOCL-BLIS zen3/4/5:
// BLIS splits K into EXACT KC panels (no GotoBLAS half-split); zen sgemm
// KC=512 => panels [512,512]. Per C element: sequential ascending-k IEEE-FMA
// chain within a panel; C := beta*C + chain per panel (beta=0 first).
// Scan: f32 numpy op order, inline-asm unfused (fixed since R10).
__global__ __launch_bounds__(256) void k1_f32chain_snn(
    const float* __restrict__ X,    // [M,K] fp32
    const float* __restrict__ W1,   // [N,K] fp32
    const float* __restrict__ b1,   // [N]
    const void* tau_mem_p, const void* tau_syn_p,
    const void* v_thresh_p, const void* v_reset_p, const void* ts_p,
    float* __restrict__ spikes,     // [M,N] fp32 integer counts
    int M, int N, int K,
    int f0, int f1, int f2)          // fold boundaries (then K)
{
    __shared__ float As[64][33];
    __shared__ float Bs[64][33];

    const int t  = threadIdx.x;
    const int tx = t & 15;
    const int ty = t >> 4;
    const int m0 = blockIdx.x * 64;
    const int n0 = blockIdx.y * 64;

    float c[4][4] = {};   // panel-folded sum
    float p[4][4] = {};   // current panel chain

    for (int k0 = 0; k0 < K; k0 += 32) {
        #pragma unroll
        for (int cc = 0; cc < 2; ++cc) {
            const int li  = cc * 256 + t;    // 0..511
            const int row = li >> 3;
            const int q   = li & 7;
            const float4 va = *(const float4*)&X[(size_t)(m0 + row) * K + k0 + q * 4];
            As[row][q * 4 + 0] = va.x; As[row][q * 4 + 1] = va.y;
            As[row][q * 4 + 2] = va.z; As[row][q * 4 + 3] = va.w;
            const float4 vb = *(const float4*)&W1[(size_t)(n0 + row) * K + k0 + q * 4];
            Bs[row][q * 4 + 0] = vb.x; Bs[row][q * 4 + 1] = vb.y;
            Bs[row][q * 4 + 2] = vb.z; Bs[row][q * 4 + 3] = vb.w;
        }
        __syncthreads();

        // strict ascending-k FMA chain (sequentially dependent, unreorderable)
        for (int kk = 0; kk < 32; ++kk) {
            float a[4], b[4];
            #pragma unroll
            for (int i = 0; i < 4; ++i) a[i] = As[ty * 4 + i][kk];
            #pragma unroll
            for (int j = 0; j < 4; ++j) b[j] = Bs[tx * 4 + j][kk];
            #pragma unroll
            for (int i = 0; i < 4; ++i)
                #pragma unroll
                for (int j = 0; j < 4; ++j)
                    p[i][j] = __builtin_fmaf(a[i], b[j], p[i][j]);
        }
        __syncthreads();

        const int ke = k0 + 32;
        if (ke == f0 || ke == f1 || ke == f2 || ke == K) {  // panel boundary
            #pragma unroll
            for (int i = 0; i < 4; ++i)
                #pragma unroll
                for (int j = 0; j < 4; ++j) {
                    c[i][j] = vaddf(c[i][j], p[i][j]);
                    p[i][j] = 0.0f;
                }
        }
    }

    // ---- f32 LIF scan, numpy op order, asm-enforced unfused ----
    const float tau_m = decode_scalar(tau_mem_p, 10.0f);
    const float tau_s = decode_scalar(tau_syn_p, 5.0f);
    const float vth   = decode_scalar(v_thresh_p, 1.0f);
    const float vrs   = decode_scalar(v_reset_p, 0.0f);
    const int   ts    = decode_ts(ts_p);
    const float rs    = 1.0f / tau_s;    // correctly-rounded f32 div = np bits
    const float rm    = 1.0f / tau_m;
    const float ivts  = 1.0f / (float)ts;  // ts=32: exact; x*(1/32) == x/32

    #pragma unroll
    for (int j = 0; j < 4; ++j) {
        const int col    = n0 + tx * 4 + j;
        const float bias = b1[col];
        float cur[4], iv[4], vv[4], cnt[4];
        #pragma unroll
        for (int i = 0; i < 4; ++i) {
            cur[i] = vmulf(vaddf(c[i][j], bias), ivts);  // exact /32
            iv[i] = 0.0f; vv[i] = 0.0f; cnt[i] = 0.0f;
        }
        for (int tt = 0; tt < ts; ++tt) {
            #pragma unroll
            for (int i = 0; i < 4; ++i) {
                // i = (i - rs*i) + cur   — three separately-rounded ops
                iv[i] = vaddf(vsubf(iv[i], vmulf(rs, iv[i])), cur[i]);
                // v = (v - rm*v) + i
                vv[i] = vaddf(vsubf(vv[i], vmulf(rm, vv[i])), iv[i]);
                const bool s = (vv[i] >= vth);
                cnt[i] += s ? 1.0f : 0.0f;
                vv[i]   = s ? vrs : vv[i];
            }
        }
        #pragma unroll
        for (int i = 0; i < 4; ++i)
            spikes[(size_t)(m0 + ty * 4 + i) * N + col] = cnt[i];
    }
}

// ---------------- k2: out = spikes @ W2^T + b2 (MFMA bf16-split) ----------
// Counts exact in bf16; W2 2-split ~1e-5 accuracy vs 0.18 tolerance.
// Verified: output 0 passed rounds 4-16 with this kernel.
__global__ __launch_bounds__(256) void k2_gemm(
    const float* __restrict__ S,    // [M,K2] fp32 spike counts
    const float* __restrict__ W2,   // [N2,K2] fp32
    const float* __restrict__ b2,   // [N2]
    float* __restrict__ out,        // [M,N2] fp32
    int M, int N2, int K2)
{
    __shared__ __align__(16) short Sa[64 * 32];
    __shared__ __align__(16) short Bh[64 * 32];
    __shared__ __align__(16) short Bm[64 * 32];

    const int t    = threadIdx.x;
    const int l    = t & 63;
    const int w    = t >> 6;
    const int quad = l >> 4;
    const int r    = l & 15;
    const int wm   = w & 1;
    const int wn   = w >> 1;

    const int m0 = blockIdx.x * 64;
    const int n0 = blockIdx.y * 64;

    f32x4 acc[2][2] = {};

    for (int k0 = 0; k0 < K2; k0 += 32) {
        #pragma unroll
        for (int cc = 0; cc < 2; ++cc) {
            const int li  = cc * 256 + t;
            const int row = li >> 3;
            const int q   = li & 7;
            const float4 vs = *(const float4*)&S[(size_t)(m0 + row) * K2 + k0 + q * 4];
            *(short4*)&Sa[row * 32 + q * 4] =
                make_short4(bf16h(vs.x), bf16h(vs.y), bf16h(vs.z), bf16h(vs.w));
            const float4 vb = *(const float4*)&W2[(size_t)(n0 + row) * K2 + k0 + q * 4];
            short h[4], m_[4];
            split2(vb.x, h[0], m_[0]); split2(vb.y, h[1], m_[1]);
            split2(vb.z, h[2], m_[2]); split2(vb.w, h[3], m_[3]);
            *(short4*)&Bh[row * 32 + q * 4] = make_short4(h[0], h[1], h[2], h[3]);
            *(short4*)&Bm[row * 32 + q * 4] = make_short4(m_[0], m_[1], m_[2], m_[3]);
        }
        __syncthreads();

        bf16x8 af[2], bh[2], bm[2];
        #pragma unroll
        for (int i = 0; i < 2; ++i) {
            af[i] = *(const bf16x8*)&Sa[(wm * 32 + i * 16 + r) * 32 + quad * 8];
            bh[i] = *(const bf16x8*)&Bh[(wn * 32 + i * 16 + r) * 32 + quad * 8];
            bm[i] = *(const bf16x8*)&Bm[(wn * 32 + i * 16 + r) * 32 + quad * 8];
        }
        #pragma unroll
        for (int i = 0; i < 2; ++i)
            #pragma unroll
            for (int j = 0; j < 2; ++j) {
                acc[i][j] = __builtin_amdgcn_mfma_f32_16x16x32_bf16(af[i], bh[j], acc[i][j], 0, 0, 0);
                acc[i][j] = __builtin_amdgcn_mfma_f32_16x16x32_bf16(af[i], bm[j], acc[i][j], 0, 0, 0);
            }
        __syncthreads();
    }

    #pragma unroll
    for (int j = 0; j < 2; ++j) {
        const int col = n0 + wn * 32 + j * 16 + r;
        const float bias = b2[col];
        #pragma unroll
        for (int i = 0; i < 2; ++i) {
            const int rowb = m0 + wm * 32 + i * 16 + quad * 4;
            #pragma unroll
            for (int e = 0; e < 4; ++e)
                out[(size_t)(rowb + e) * N2 + col] = __fadd_rn(acc[i][j][e], bias);
        }
    }
}

extern "C" void kernel_launch(void* const* d_in, const int* in_sizes, int n_in,
                              void* d_out, int out_size, void* d_ws, size_t ws_size,
                              hipStream_t stream) {
    (void)n_in; (void)d_ws; (void)ws_size; (void)out_size;

    const float* X  = (const float*)d_in[0];
    const float* W1 = (const float*)d_in[1];
    const float* b1 = (const float*)d_in[2];
    const float* W2 = (const float*)d_in[3];
    const float* b2 = (const float*)d_in[4];
    const void* tau_mem = d_in[5];
    const void* tau_syn = d_in[6];
    const void* vth     = d_in[7];
    const void* vrs     = d_in[8];
    const void* ts      = d_in[11];

    const int H   = in_sizes[2];             // 2048
    const int IN  = in_sizes[1] / H;         // 1024
    const int OUT = in_sizes[4];             // 256
    const int B   = in_sizes[0] / IN;        // 4096

    float* out    = (float*)d_out;           // [B, OUT] fp32
    float* spikes = out + (size_t)B * OUT;   // [B, H]  fp32

    // R17: BLIS/AOCL-zen exact-KC panels, KC=512 => folds at 512 only
    // (panels [512,512]). Next if falsified: V2-mixed (f64 matmul + f64
    // bias/div -> f32 scan), then even/odd dual-acc sub-chains.
    const int f0 = 512;

    dim3 g1(B / 64, H / 64);
    k1_f32chain_snn<<<g1, 256, 0, stream>>>(X, W1, b1, tau_mem, tau_syn, vth, vrs, ts,
                                            spikes, B, H, IN,
                                            f0, IN, IN);

    dim3 g2(B / 64, OUT / 64);
    k2_gemm<<<g2, 256, 0, stream>>>(spikes, W2, b2, out, B, OUT, H);
}

// Round 18
// 560.339 us; speedup vs baseline: 1.0116x; 1.0116x over previous
//
#include <hip/hip_runtime.h>
#include <hip/hip_bf16.h>
#include <stdint.h>

typedef __attribute__((ext_vector_type(8))) short bf16x8;
typedef __attribute__((ext_vector_type(4))) float f32x4;

// Contraction-proof single f32 ops (np emulation must stay unfused).
__device__ __forceinline__ float vmulf(float a, float b) {
    float d; asm volatile("v_mul_f32 %0, %1, %2" : "=v"(d) : "v"(a), "v"(b)); return d;
}
__device__ __forceinline__ float vaddf(float a, float b) {
    float d; asm volatile("v_add_f32 %0, %1, %2" : "=v"(d) : "v"(a), "v"(b)); return d;
}
__device__ __forceinline__ float vsubf(float a, float b) {
    float d; asm volatile("v_sub_f32 %0, %1, %2" : "=v"(d) : "v"(a), "v"(b)); return d;
}

__device__ __forceinline__ short bf16h(float v) {
    __hip_bfloat16 h = __float2bfloat16(v);
    return *(short*)&h;
}
__device__ __forceinline__ float bf16f(short s) {
    return __uint_as_float(((unsigned int)(unsigned short)s) << 16);
}
__device__ __forceinline__ void split2(float v, short& h, short& m) {
    h = bf16h(v);
    m = bf16h(__fsub_rn(v, bf16f(h)));
}

__device__ __forceinline__ float decode_scalar(const void* p, float dflt) {
    float f = *(const float*)p;
    if (!(f == f) || fabsf(f) > 1.0e6f) return dflt;
    return f;
}
__device__ __forceinline__ int decode_ts(const void* p) {
    int w = *(const int*)p;
    if (w >= 1 && w <= 100000) return w;
    return 32;
}

#define LDA 36   // LDS row stride: 16B-aligned b128 at kk%4==0; banks spread

// ---------------- k1: bit-exact np-f32 pipeline (VERIFIED R17) --------------
// Reference = AOCL-BLIS zen sgemm: exact KC=512 panels [512,512]; per C
// element a sequential ascending-k IEEE-FMA chain within each panel,
// C = P0 + P1 folded in order. Scan: f32 numpy op order, inline-asm unfused.
// R18 optimization: 128x128 tile, 8x8 elems/thread (interleaved m=ty+16i,
// n=tx+16j), LDS stride 36 -> ds_read_b128 along k (4 k/read; FMA order
// inside the float4 preserved => chain bits unchanged).
__global__ __launch_bounds__(256) void k1_f32chain_snn(
    const float* __restrict__ X,    // [M,K] fp32
    const float* __restrict__ W1,   // [N,K] fp32
    const float* __restrict__ b1,   // [N]
    const void* tau_mem_p, const void* tau_syn_p,
    const void* v_thresh_p, const void* v_reset_p, const void* ts_p,
    float* __restrict__ spikes,     // [M,N] fp32 integer counts
    int M, int N, int K, int f0)    // fold boundary (then K)
{
    __shared__ float As[128][LDA];
    __shared__ float Bs[128][LDA];

    const int t  = threadIdx.x;
    const int tx = t & 15;
    const int ty = t >> 4;
    const int m0 = blockIdx.x * 128;
    const int n0 = blockIdx.y * 128;

    float c[8][8] = {};   // panel-folded sum
    float p[8][8] = {};   // current panel chain

    for (int k0 = 0; k0 < K; k0 += 32) {
        // Stage 128 rows x 32 k for A and B: 1024 float4 each, 4/thread.
        #pragma unroll
        for (int cc = 0; cc < 4; ++cc) {
            const int li  = cc * 256 + t;    // 0..1023
            const int row = li >> 3;
            const int q   = li & 7;
            *(float4*)&As[row][q * 4] =
                *(const float4*)&X[(size_t)(m0 + row) * K + k0 + q * 4];
            *(float4*)&Bs[row][q * 4] =
                *(const float4*)&W1[(size_t)(n0 + row) * K + k0 + q * 4];
        }
        __syncthreads();

        // 8 groups of 4 k; within each float4 the FMAs are applied in k
        // order, so the per-element chain remains strictly ascending-k.
        #pragma unroll
        for (int g = 0; g < 8; ++g) {
            float4 af[8], bf[8];
            #pragma unroll
            for (int i = 0; i < 8; ++i)
                af[i] = *(const float4*)&As[ty + 16 * i][g * 4];
            #pragma unroll
            for (int j = 0; j < 8; ++j)
                bf[j] = *(const float4*)&Bs[tx + 16 * j][g * 4];
            #pragma unroll
            for (int kk = 0; kk < 4; ++kk) {
                #pragma unroll
                for (int i = 0; i < 8; ++i) {
                    const float a = ((const float*)&af[i])[kk];
                    #pragma unroll
                    for (int j = 0; j < 8; ++j)
                        p[i][j] = __builtin_fmaf(a, ((const float*)&bf[j])[kk], p[i][j]);
                }
            }
        }
        __syncthreads();

        const int ke = k0 + 32;
        if (ke == f0 || ke == K) {            // BLIS panel boundary: fold
            #pragma unroll
            for (int i = 0; i < 8; ++i)
                #pragma unroll
                for (int j = 0; j < 8; ++j) {
                    c[i][j] = vaddf(c[i][j], p[i][j]);
                    p[i][j] = 0.0f;
                }
        }
    }

    // ---- f32 LIF scan, numpy op order, asm-enforced unfused ----
    const float tau_m = decode_scalar(tau_mem_p, 10.0f);
    const float tau_s = decode_scalar(tau_syn_p, 5.0f);
    const float vth   = decode_scalar(v_thresh_p, 1.0f);
    const float vrs   = decode_scalar(v_reset_p, 0.0f);
    const int   ts    = decode_ts(ts_p);
    const float rs    = 1.0f / tau_s;      // correctly-rounded f32 div = np bits
    const float rm    = 1.0f / tau_m;
    const float ivts  = 1.0f / (float)ts;  // ts=32: exact; x*(1/32) == x/32

    #pragma unroll
    for (int j = 0; j < 8; ++j) {
        const int col    = n0 + tx + 16 * j;
        const float bias = b1[col];
        float cur[8], iv[8], vv[8], cnt[8];
        #pragma unroll
        for (int i = 0; i < 8; ++i) {
            cur[i] = vmulf(vaddf(c[i][j], bias), ivts);  // exact /32
            iv[i] = 0.0f; vv[i] = 0.0f; cnt[i] = 0.0f;
        }
        for (int tt = 0; tt < ts; ++tt) {
            #pragma unroll
            for (int i = 0; i < 8; ++i) {
                // i = (i - rs*i) + cur   — three separately-rounded ops
                iv[i] = vaddf(vsubf(iv[i], vmulf(rs, iv[i])), cur[i]);
                // v = (v - rm*v) + i
                vv[i] = vaddf(vsubf(vv[i], vmulf(rm, vv[i])), iv[i]);
                const bool s = (vv[i] >= vth);
                cnt[i] += s ? 1.0f : 0.0f;
                vv[i]   = s ? vrs : vv[i];
            }
        }
        #pragma unroll
        for (int i = 0; i < 8; ++i)
            spikes[(size_t)(m0 + ty + 16 * i) * N + col] = cnt[i];
    }
}

// ---------------- k2: out = spikes @ W2^T + b2 (MFMA bf16-split) ----------
// Counts exact in bf16; W2 2-split ~1e-5 accuracy vs 0.18 tolerance.
// Verified: output 0 passed rounds 4-17 with this kernel.
__global__ __launch_bounds__(256) void k2_gemm(
    const float* __restrict__ S,    // [M,K2] fp32 spike counts
    const float* __restrict__ W2,   // [N2,K2] fp32
    const float* __restrict__ b2,   // [N2]
    float* __restrict__ out,        // [M,N2] fp32
    int M, int N2, int K2)
{
    __shared__ __align__(16) short Sa[64 * 32];
    __shared__ __align__(16) short Bh[64 * 32];
    __shared__ __align__(16) short Bm[64 * 32];

    const int t    = threadIdx.x;
    const int l    = t & 63;
    const int w    = t >> 6;
    const int quad = l >> 4;
    const int r    = l & 15;
    const int wm   = w & 1;
    const int wn   = w >> 1;

    const int m0 = blockIdx.x * 64;
    const int n0 = blockIdx.y * 64;

    f32x4 acc[2][2] = {};

    for (int k0 = 0; k0 < K2; k0 += 32) {
        #pragma unroll
        for (int cc = 0; cc < 2; ++cc) {
            const int li  = cc * 256 + t;
            const int row = li >> 3;
            const int q   = li & 7;
            const float4 vs = *(const float4*)&S[(size_t)(m0 + row) * K2 + k0 + q * 4];
            *(short4*)&Sa[row * 32 + q * 4] =
                make_short4(bf16h(vs.x), bf16h(vs.y), bf16h(vs.z), bf16h(vs.w));
            const float4 vb = *(const float4*)&W2[(size_t)(n0 + row) * K2 + k0 + q * 4];
            short h[4], m_[4];
            split2(vb.x, h[0], m_[0]); split2(vb.y, h[1], m_[1]);
            split2(vb.z, h[2], m_[2]); split2(vb.w, h[3], m_[3]);
            *(short4*)&Bh[row * 32 + q * 4] = make_short4(h[0], h[1], h[2], h[3]);
            *(short4*)&Bm[row * 32 + q * 4] = make_short4(m_[0], m_[1], m_[2], m_[3]);
        }
        __syncthreads();

        bf16x8 af[2], bh[2], bm[2];
        #pragma unroll
        for (int i = 0; i < 2; ++i) {
            af[i] = *(const bf16x8*)&Sa[(wm * 32 + i * 16 + r) * 32 + quad * 8];
            bh[i] = *(const bf16x8*)&Bh[(wn * 32 + i * 16 + r) * 32 + quad * 8];
            bm[i] = *(const bf16x8*)&Bm[(wn * 32 + i * 16 + r) * 32 + quad * 8];
        }
        #pragma unroll
        for (int i = 0; i < 2; ++i)
            #pragma unroll
            for (int j = 0; j < 2; ++j) {
                acc[i][j] = __builtin_amdgcn_mfma_f32_16x16x32_bf16(af[i], bh[j], acc[i][j], 0, 0, 0);
                acc[i][j] = __builtin_amdgcn_mfma_f32_16x16x32_bf16(af[i], bm[j], acc[i][j], 0, 0, 0);
            }
        __syncthreads();
    }

    #pragma unroll
    for (int j = 0; j < 2; ++j) {
        const int col = n0 + wn * 32 + j * 16 + r;
        const float bias = b2[col];
        #pragma unroll
        for (int i = 0; i < 2; ++i) {
            const int rowb = m0 + wm * 32 + i * 16 + quad * 4;
            #pragma unroll
            for (int e = 0; e < 4; ++e)
                out[(size_t)(rowb + e) * N2 + col] = __fadd_rn(acc[i][j][e], bias);
        }
    }
}

extern "C" void kernel_launch(void* const* d_in, const int* in_sizes, int n_in,
                              void* d_out, int out_size, void* d_ws, size_t ws_size,
                              hipStream_t stream) {
    (void)n_in; (void)d_ws; (void)ws_size; (void)out_size;

    const float* X  = (const float*)d_in[0];
    const float* W1 = (const float*)d_in[1];
    const float* b1 = (const float*)d_in[2];
    const float* W2 = (const float*)d_in[3];
    const float* b2 = (const float*)d_in[4];
    const void* tau_mem = d_in[5];
    const void* tau_syn = d_in[6];
    const void* vth     = d_in[7];
    const void* vrs     = d_in[8];
    const void* ts      = d_in[11];

    const int H   = in_sizes[2];             // 2048
    const int IN  = in_sizes[1] / H;         // 1024
    const int OUT = in_sizes[4];             // 256
    const int B   = in_sizes[0] / IN;        // 4096

    float* out    = (float*)d_out;           // [B, OUT] fp32
    float* spikes = out + (size_t)B * OUT;   // [B, H]  fp32

    // VERIFIED (R17): AOCL-BLIS zen KC=512 -> single fold at k=512.
    const int f0 = 512;

    dim3 g1(B / 128, H / 128);
    k1_f32chain_snn<<<g1, 256, 0, stream>>>(X, W1, b1, tau_mem, tau_syn, vth, vrs, ts,
                                            spikes, B, H, IN, f0);

    dim3 g2(B / 64, OUT / 64);
    k2_gemm<<<g2, 256, 0, stream>>>(spikes, W2, b2, out, B, OUT, H);
}

// Round 19
// 448.701 us; speedup vs baseline: 1.2632x; 1.2488x over previous
//
#include <hip/hip_runtime.h>
#include <hip/hip_bf16.h>
#include <stdint.h>

typedef __attribute__((ext_vector_type(8))) short bf16x8;
typedef __attribute__((ext_vector_type(4))) float f32x4;

// Contraction-proof single f32 ops (np emulation must stay unfused).
__device__ __forceinline__ float vmulf(float a, float b) {
    float d; asm volatile("v_mul_f32 %0, %1, %2" : "=v"(d) : "v"(a), "v"(b)); return d;
}
__device__ __forceinline__ float vaddf(float a, float b) {
    float d; asm volatile("v_add_f32 %0, %1, %2" : "=v"(d) : "v"(a), "v"(b)); return d;
}
__device__ __forceinline__ float vsubf(float a, float b) {
    float d; asm volatile("v_sub_f32 %0, %1, %2" : "=v"(d) : "v"(a), "v"(b)); return d;
}

__device__ __forceinline__ short bf16h(float v) {
    __hip_bfloat16 h = __float2bfloat16(v);
    return *(short*)&h;
}
__device__ __forceinline__ float bf16f(short s) {
    return __uint_as_float(((unsigned int)(unsigned short)s) << 16);
}
__device__ __forceinline__ void split2(float v, short& h, short& m) {
    h = bf16h(v);
    m = bf16h(__fsub_rn(v, bf16f(h)));
}

__device__ __forceinline__ float decode_scalar(const void* p, float dflt) {
    float f = *(const float*)p;
    if (!(f == f) || fabsf(f) > 1.0e6f) return dflt;
    return f;
}
__device__ __forceinline__ int decode_ts(const void* p) {
    int w = *(const int*)p;
    if (w >= 1 && w <= 100000) return w;
    return 32;
}

#define LDA 36   // LDS row stride: 16B-aligned b128; tx*36%32 -> 2-way (free)

// -------- k1a: one BLIS KC=512 panel per block (exact ascending-k chain) ----
// Reference (VERIFIED R17/R18) = AOCL-BLIS zen sgemm: exact KC=512 panels,
// sequential ascending-k IEEE-FMA chain per C element, C = P0 + P1 in order.
// This kernel computes ONE panel chain (blockIdx.z selects k-range) holding
// only p[8][8] (no fold sum) -> VGPR ~100, grid 1024 blocks = 4/CU.
__global__ __launch_bounds__(256) void k1_panel_gemm(
    const float* __restrict__ X,    // [M,K] fp32
    const float* __restrict__ W1,   // [N,K] fp32
    float* __restrict__ P0,         // [M,N] panel-0 out (spikes buffer)
    float* __restrict__ P1,         // [M,N] panel-1 out (workspace)
    int M, int N, int K, int KC)
{
    __shared__ float As[128][LDA];
    __shared__ float Bs[128][LDA];

    const int t  = threadIdx.x;
    const int tx = t & 15;
    const int ty = t >> 4;
    const int m0 = blockIdx.x * 128;
    const int n0 = blockIdx.y * 128;
    const int kz = blockIdx.z * KC;
    float* __restrict__ Pout = blockIdx.z ? P1 : P0;

    float p[8][8] = {};   // this panel's sequential chain

    for (int k0 = kz; k0 < kz + KC; k0 += 32) {
        #pragma unroll
        for (int cc = 0; cc < 4; ++cc) {
            const int li  = cc * 256 + t;    // 0..1023
            const int row = li >> 3;
            const int q   = li & 7;
            *(float4*)&As[row][q * 4] =
                *(const float4*)&X[(size_t)(m0 + row) * K + k0 + q * 4];
            *(float4*)&Bs[row][q * 4] =
                *(const float4*)&W1[(size_t)(n0 + row) * K + k0 + q * 4];
        }
        __syncthreads();

        // 8 groups of 4 k; FMAs applied in ascending k inside each float4,
        // so the per-element chain is strictly ascending-k (bit-exact).
        #pragma unroll
        for (int g = 0; g < 8; ++g) {
            float4 af[8], bf[8];
            #pragma unroll
            for (int i = 0; i < 8; ++i)
                af[i] = *(const float4*)&As[ty + 16 * i][g * 4];
            #pragma unroll
            for (int j = 0; j < 8; ++j)
                bf[j] = *(const float4*)&Bs[tx + 16 * j][g * 4];
            #pragma unroll
            for (int kk = 0; kk < 4; ++kk) {
                #pragma unroll
                for (int i = 0; i < 8; ++i) {
                    const float a = ((const float*)&af[i])[kk];
                    #pragma unroll
                    for (int j = 0; j < 8; ++j)
                        p[i][j] = __builtin_fmaf(a, ((const float*)&bf[j])[kk], p[i][j]);
                }
            }
        }
        __syncthreads();
    }

    #pragma unroll
    for (int i = 0; i < 8; ++i) {
        const size_t rowb = (size_t)(m0 + ty + 16 * i) * N;
        #pragma unroll
        for (int j = 0; j < 8; ++j)
            Pout[rowb + n0 + tx + 16 * j] = p[i][j];
    }
}

// -------- k1b: fold c = P0 + P1 (BLIS order) + exact f32 asm-unfused scan ---
__global__ __launch_bounds__(256) void k1_combine_scan(
    const float* __restrict__ P0,   // aliases spikes (read-then-overwrite ok)
    const float* __restrict__ P1,
    const float* __restrict__ b1,
    const void* tau_mem_p, const void* tau_syn_p,
    const void* v_thresh_p, const void* v_reset_p, const void* ts_p,
    float* __restrict__ spikes, int N, int total4)
{
    const int idx4 = blockIdx.x * 256 + threadIdx.x;
    if (idx4 >= total4) return;

    const float tau_m = decode_scalar(tau_mem_p, 10.0f);
    const float tau_s = decode_scalar(tau_syn_p, 5.0f);
    const float vth   = decode_scalar(v_thresh_p, 1.0f);
    const float vrs   = decode_scalar(v_reset_p, 0.0f);
    const int   ts    = decode_ts(ts_p);
    const float rs    = 1.0f / tau_s;
    const float rm    = 1.0f / tau_m;
    const float ivts  = 1.0f / (float)ts;

    const float4 a = ((const float4*)P0)[idx4];
    const float4 b = ((const float4*)P1)[idx4];
    const int col0 = (idx4 * 4) % N;                 // N % 4 == 0
    const float4 bb = *(const float4*)&b1[col0];

    float cur[4], iv[4], vv[4], cnt[4];
    const float av[4] = {a.x, a.y, a.z, a.w};
    const float bv[4] = {b.x, b.y, b.z, b.w};
    const float bbv[4] = {bb.x, bb.y, bb.z, bb.w};
    #pragma unroll
    for (int e = 0; e < 4; ++e) {
        const float c = vaddf(av[e], bv[e]);         // BLIS fold: P0 + P1
        cur[e] = vmulf(vaddf(c, bbv[e]), ivts);      // exact /32
        iv[e] = 0.0f; vv[e] = 0.0f; cnt[e] = 0.0f;
    }
    for (int tt = 0; tt < ts; ++tt) {
        #pragma unroll
        for (int e = 0; e < 4; ++e) {
            iv[e] = vaddf(vsubf(iv[e], vmulf(rs, iv[e])), cur[e]);
            vv[e] = vaddf(vsubf(vv[e], vmulf(rm, vv[e])), iv[e]);
            const bool s = (vv[e] >= vth);
            cnt[e] += s ? 1.0f : 0.0f;
            vv[e]   = s ? vrs : vv[e];
        }
    }
    ((float4*)spikes)[idx4] = make_float4(cnt[0], cnt[1], cnt[2], cnt[3]);
}

// -------- fallback k1 (R18, verified): used when ws_size is too small -------
__global__ __launch_bounds__(256) void k1_f32chain_snn(
    const float* __restrict__ X, const float* __restrict__ W1,
    const float* __restrict__ b1,
    const void* tau_mem_p, const void* tau_syn_p,
    const void* v_thresh_p, const void* v_reset_p, const void* ts_p,
    float* __restrict__ spikes, int M, int N, int K, int f0)
{
    __shared__ float As[128][LDA];
    __shared__ float Bs[128][LDA];

    const int t  = threadIdx.x;
    const int tx = t & 15;
    const int ty = t >> 4;
    const int m0 = blockIdx.x * 128;
    const int n0 = blockIdx.y * 128;

    float c[8][8] = {};
    float p[8][8] = {};

    for (int k0 = 0; k0 < K; k0 += 32) {
        #pragma unroll
        for (int cc = 0; cc < 4; ++cc) {
            const int li  = cc * 256 + t;
            const int row = li >> 3;
            const int q   = li & 7;
            *(float4*)&As[row][q * 4] =
                *(const float4*)&X[(size_t)(m0 + row) * K + k0 + q * 4];
            *(float4*)&Bs[row][q * 4] =
                *(const float4*)&W1[(size_t)(n0 + row) * K + k0 + q * 4];
        }
        __syncthreads();
        #pragma unroll
        for (int g = 0; g < 8; ++g) {
            float4 af[8], bf[8];
            #pragma unroll
            for (int i = 0; i < 8; ++i)
                af[i] = *(const float4*)&As[ty + 16 * i][g * 4];
            #pragma unroll
            for (int j = 0; j < 8; ++j)
                bf[j] = *(const float4*)&Bs[tx + 16 * j][g * 4];
            #pragma unroll
            for (int kk = 0; kk < 4; ++kk) {
                #pragma unroll
                for (int i = 0; i < 8; ++i) {
                    const float a = ((const float*)&af[i])[kk];
                    #pragma unroll
                    for (int j = 0; j < 8; ++j)
                        p[i][j] = __builtin_fmaf(a, ((const float*)&bf[j])[kk], p[i][j]);
                }
            }
        }
        __syncthreads();
        const int ke = k0 + 32;
        if (ke == f0 || ke == K) {
            #pragma unroll
            for (int i = 0; i < 8; ++i)
                #pragma unroll
                for (int j = 0; j < 8; ++j) {
                    c[i][j] = vaddf(c[i][j], p[i][j]);
                    p[i][j] = 0.0f;
                }
        }
    }

    const float tau_m = decode_scalar(tau_mem_p, 10.0f);
    const float tau_s = decode_scalar(tau_syn_p, 5.0f);
    const float vth   = decode_scalar(v_thresh_p, 1.0f);
    const float vrs   = decode_scalar(v_reset_p, 0.0f);
    const int   ts    = decode_ts(ts_p);
    const float rs    = 1.0f / tau_s;
    const float rm    = 1.0f / tau_m;
    const float ivts  = 1.0f / (float)ts;

    #pragma unroll
    for (int j = 0; j < 8; ++j) {
        const int col    = n0 + tx + 16 * j;
        const float bias = b1[col];
        float cur[8], iv[8], vv[8], cnt[8];
        #pragma unroll
        for (int i = 0; i < 8; ++i) {
            cur[i] = vmulf(vaddf(c[i][j], bias), ivts);
            iv[i] = 0.0f; vv[i] = 0.0f; cnt[i] = 0.0f;
        }
        for (int tt = 0; tt < ts; ++tt) {
            #pragma unroll
            for (int i = 0; i < 8; ++i) {
                iv[i] = vaddf(vsubf(iv[i], vmulf(rs, iv[i])), cur[i]);
                vv[i] = vaddf(vsubf(vv[i], vmulf(rm, vv[i])), iv[i]);
                const bool s = (vv[i] >= vth);
                cnt[i] += s ? 1.0f : 0.0f;
                vv[i]   = s ? vrs : vv[i];
            }
        }
        #pragma unroll
        for (int i = 0; i < 8; ++i)
            spikes[(size_t)(m0 + ty + 16 * i) * N + col] = cnt[i];
    }
}

// ---------------- k2: out = spikes @ W2^T + b2 (MFMA bf16-split) ----------
// Verified: output 0 passed rounds 4-18 with this kernel.
__global__ __launch_bounds__(256) void k2_gemm(
    const float* __restrict__ S, const float* __restrict__ W2,
    const float* __restrict__ b2, float* __restrict__ out,
    int M, int N2, int K2)
{
    __shared__ __align__(16) short Sa[64 * 32];
    __shared__ __align__(16) short Bh[64 * 32];
    __shared__ __align__(16) short Bm[64 * 32];

    const int t    = threadIdx.x;
    const int l    = t & 63;
    const int w    = t >> 6;
    const int quad = l >> 4;
    const int r    = l & 15;
    const int wm   = w & 1;
    const int wn   = w >> 1;

    const int m0 = blockIdx.x * 64;
    const int n0 = blockIdx.y * 64;

    f32x4 acc[2][2] = {};

    for (int k0 = 0; k0 < K2; k0 += 32) {
        #pragma unroll
        for (int cc = 0; cc < 2; ++cc) {
            const int li  = cc * 256 + t;
            const int row = li >> 3;
            const int q   = li & 7;
            const float4 vs = *(const float4*)&S[(size_t)(m0 + row) * K2 + k0 + q * 4];
            *(short4*)&Sa[row * 32 + q * 4] =
                make_short4(bf16h(vs.x), bf16h(vs.y), bf16h(vs.z), bf16h(vs.w));
            const float4 vb = *(const float4*)&W2[(size_t)(n0 + row) * K2 + k0 + q * 4];
            short h[4], m_[4];
            split2(vb.x, h[0], m_[0]); split2(vb.y, h[1], m_[1]);
            split2(vb.z, h[2], m_[2]); split2(vb.w, h[3], m_[3]);
            *(short4*)&Bh[row * 32 + q * 4] = make_short4(h[0], h[1], h[2], h[3]);
            *(short4*)&Bm[row * 32 + q * 4] = make_short4(m_[0], m_[1], m_[2], m_[3]);
        }
        __syncthreads();

        bf16x8 af[2], bh[2], bm[2];
        #pragma unroll
        for (int i = 0; i < 2; ++i) {
            af[i] = *(const bf16x8*)&Sa[(wm * 32 + i * 16 + r) * 32 + quad * 8];
            bh[i] = *(const bf16x8*)&Bh[(wn * 32 + i * 16 + r) * 32 + quad * 8];
            bm[i] = *(const bf16x8*)&Bm[(wn * 32 + i * 16 + r) * 32 + quad * 8];
        }
        #pragma unroll
        for (int i = 0; i < 2; ++i)
            #pragma unroll
            for (int j = 0; j < 2; ++j) {
                acc[i][j] = __builtin_amdgcn_mfma_f32_16x16x32_bf16(af[i], bh[j], acc[i][j], 0, 0, 0);
                acc[i][j] = __builtin_amdgcn_mfma_f32_16x16x32_bf16(af[i], bm[j], acc[i][j], 0, 0, 0);
            }
        __syncthreads();
    }

    #pragma unroll
    for (int j = 0; j < 2; ++j) {
        const int col = n0 + wn * 32 + j * 16 + r;
        const float bias = b2[col];
        #pragma unroll
        for (int i = 0; i < 2; ++i) {
            const int rowb = m0 + wm * 32 + i * 16 + quad * 4;
            #pragma unroll
            for (int e = 0; e < 4; ++e)
                out[(size_t)(rowb + e) * N2 + col] = __fadd_rn(acc[i][j][e], bias);
        }
    }
}

extern "C" void kernel_launch(void* const* d_in, const int* in_sizes, int n_in,
                              void* d_out, int out_size, void* d_ws, size_t ws_size,
                              hipStream_t stream) {
    (void)n_in; (void)out_size;

    const float* X  = (const float*)d_in[0];
    const float* W1 = (const float*)d_in[1];
    const float* b1 = (const float*)d_in[2];
    const float* W2 = (const float*)d_in[3];
    const float* b2 = (const float*)d_in[4];
    const void* tau_mem = d_in[5];
    const void* tau_syn = d_in[6];
    const void* vth     = d_in[7];
    const void* vrs     = d_in[8];
    const void* ts      = d_in[11];

    const int H   = in_sizes[2];             // 2048
    const int IN  = in_sizes[1] / H;         // 1024
    const int OUT = in_sizes[4];             // 256
    const int B   = in_sizes[0] / IN;        // 4096

    float* out    = (float*)d_out;           // [B, OUT] fp32
    float* spikes = out + (size_t)B * OUT;   // [B, H]  fp32

    const int KC = 512;                      // VERIFIED: AOCL-BLIS zen KC
    const size_t panel_bytes = (size_t)B * H * sizeof(float);

    if (IN == 2 * KC && ws_size >= panel_bytes && ((uintptr_t)d_ws % 16 == 0)) {
        // Split-K panel path: P0 -> spikes buffer, P1 -> workspace.
        float* P1 = (float*)d_ws;
        dim3 g1(B / 128, H / 128, 2);
        k1_panel_gemm<<<g1, 256, 0, stream>>>(X, W1, spikes, P1, B, H, IN, KC);

        const int total4 = (B * H) / 4;
        k1_combine_scan<<<(total4 + 255) / 256, 256, 0, stream>>>(
            spikes, P1, b1, tau_mem, tau_syn, vth, vrs, ts, spikes, H, total4);
    } else {
        // Fallback: verified single-pass R18 kernel.
        dim3 g1(B / 128, H / 128);
        k1_f32chain_snn<<<g1, 256, 0, stream>>>(X, W1, b1, tau_mem, tau_syn, vth, vrs, ts,
                                                spikes, B, H, IN, KC);
    }

    dim3 g2(B / 64, OUT / 64);
    k2_gemm<<<g2, 256, 0, stream>>>(spikes, W2, b2, out, B, OUT, H);
}

// Round 20
// 426.611 us; speedup vs baseline: 1.3287x; 1.0518x over previous
//
#include <hip/hip_runtime.h>
#include <hip/hip_bf16.h>
#include <stdint.h>

typedef __attribute__((ext_vector_type(8))) short bf16x8;
typedef __attribute__((ext_vector_type(4))) float f32x4;

// Contraction-proof single f32 ops (np emulation must stay unfused).
__device__ __forceinline__ float vmulf(float a, float b) {
    float d; asm volatile("v_mul_f32 %0, %1, %2" : "=v"(d) : "v"(a), "v"(b)); return d;
}
__device__ __forceinline__ float vaddf(float a, float b) {
    float d; asm volatile("v_add_f32 %0, %1, %2" : "=v"(d) : "v"(a), "v"(b)); return d;
}
__device__ __forceinline__ float vsubf(float a, float b) {
    float d; asm volatile("v_sub_f32 %0, %1, %2" : "=v"(d) : "v"(a), "v"(b)); return d;
}

__device__ __forceinline__ short bf16h(float v) {
    __hip_bfloat16 h = __float2bfloat16(v);
    return *(short*)&h;
}
__device__ __forceinline__ float bf16f(short s) {
    return __uint_as_float(((unsigned int)(unsigned short)s) << 16);
}
__device__ __forceinline__ void split2(float v, short& h, short& m) {
    h = bf16h(v);
    m = bf16h(__fsub_rn(v, bf16f(h)));
}

__device__ __forceinline__ float decode_scalar(const void* p, float dflt) {
    float f = *(const float*)p;
    if (!(f == f) || fabsf(f) > 1.0e6f) return dflt;
    return f;
}
__device__ __forceinline__ int decode_ts(const void* p) {
    int w = *(const int*)p;
    if (w >= 1 && w <= 100000) return w;
    return 32;
}

#define LDA 36   // LDS row stride: 16B-aligned b128; balanced bank use

// -------- k1a: one BLIS KC=512 panel per block (exact ascending-k chain) ----
// Reference (VERIFIED R17-R19) = AOCL-BLIS zen sgemm: exact KC=512 panels,
// sequential ascending-k IEEE-FMA chain per C element, C = P0 + P1 in order.
__global__ __launch_bounds__(256) void k1_panel_gemm(
    const float* __restrict__ X,    // [M,K] fp32
    const float* __restrict__ W1,   // [N,K] fp32
    float* __restrict__ P0,         // [M,N] panel-0 out (spikes buffer)
    float* __restrict__ P1,         // [M,N] panel-1 out (workspace)
    int M, int N, int K, int KC)
{
    __shared__ float As[128][LDA];
    __shared__ float Bs[128][LDA];

    const int t  = threadIdx.x;
    const int tx = t & 15;
    const int ty = t >> 4;
    const int m0 = blockIdx.x * 128;
    const int n0 = blockIdx.y * 128;
    const int kz = blockIdx.z * KC;
    float* __restrict__ Pout = blockIdx.z ? P1 : P0;

    float p[8][8] = {};   // this panel's sequential chain

    for (int k0 = kz; k0 < kz + KC; k0 += 32) {
        #pragma unroll
        for (int cc = 0; cc < 4; ++cc) {
            const int li  = cc * 256 + t;    // 0..1023
            const int row = li >> 3;
            const int q   = li & 7;
            *(float4*)&As[row][q * 4] =
                *(const float4*)&X[(size_t)(m0 + row) * K + k0 + q * 4];
            *(float4*)&Bs[row][q * 4] =
                *(const float4*)&W1[(size_t)(n0 + row) * K + k0 + q * 4];
        }
        __syncthreads();

        #pragma unroll
        for (int g = 0; g < 8; ++g) {
            float4 af[8], bf[8];
            #pragma unroll
            for (int i = 0; i < 8; ++i)
                af[i] = *(const float4*)&As[ty + 16 * i][g * 4];
            #pragma unroll
            for (int j = 0; j < 8; ++j)
                bf[j] = *(const float4*)&Bs[tx + 16 * j][g * 4];
            #pragma unroll
            for (int kk = 0; kk < 4; ++kk) {
                #pragma unroll
                for (int i = 0; i < 8; ++i) {
                    const float a = ((const float*)&af[i])[kk];
                    #pragma unroll
                    for (int j = 0; j < 8; ++j)
                        p[i][j] = __builtin_fmaf(a, ((const float*)&bf[j])[kk], p[i][j]);
                }
            }
        }
        __syncthreads();
    }

    #pragma unroll
    for (int i = 0; i < 8; ++i) {
        const size_t rowb = (size_t)(m0 + ty + 16 * i) * N;
        #pragma unroll
        for (int j = 0; j < 8; ++j)
            Pout[rowb + n0 + tx + 16 * j] = p[i][j];
    }
}

// -------- k1b: fold c = P0 + P1 (BLIS order) + exact f32 asm-unfused scan ---
__global__ __launch_bounds__(256) void k1_combine_scan(
    const float* __restrict__ P0,
    const float* __restrict__ P1,
    const float* __restrict__ b1,
    const void* tau_mem_p, const void* tau_syn_p,
    const void* v_thresh_p, const void* v_reset_p, const void* ts_p,
    float* __restrict__ spikes, int N, int total4)
{
    const int idx4 = blockIdx.x * 256 + threadIdx.x;
    if (idx4 >= total4) return;

    const float tau_m = decode_scalar(tau_mem_p, 10.0f);
    const float tau_s = decode_scalar(tau_syn_p, 5.0f);
    const float vth   = decode_scalar(v_thresh_p, 1.0f);
    const float vrs   = decode_scalar(v_reset_p, 0.0f);
    const int   ts    = decode_ts(ts_p);
    const float rs    = 1.0f / tau_s;
    const float rm    = 1.0f / tau_m;
    const float ivts  = 1.0f / (float)ts;

    const float4 a = ((const float4*)P0)[idx4];
    const float4 b = ((const float4*)P1)[idx4];
    const int col0 = (idx4 * 4) % N;
    const float4 bb = *(const float4*)&b1[col0];

    float cur[4], iv[4], vv[4], cnt[4];
    const float av[4] = {a.x, a.y, a.z, a.w};
    const float bv[4] = {b.x, b.y, b.z, b.w};
    const float bbv[4] = {bb.x, bb.y, bb.z, bb.w};
    #pragma unroll
    for (int e = 0; e < 4; ++e) {
        const float c = vaddf(av[e], bv[e]);         // BLIS fold: P0 + P1
        cur[e] = vmulf(vaddf(c, bbv[e]), ivts);      // exact /32
        iv[e] = 0.0f; vv[e] = 0.0f; cnt[e] = 0.0f;
    }
    for (int tt = 0; tt < ts; ++tt) {
        #pragma unroll
        for (int e = 0; e < 4; ++e) {
            iv[e] = vaddf(vsubf(iv[e], vmulf(rs, iv[e])), cur[e]);
            vv[e] = vaddf(vsubf(vv[e], vmulf(rm, vv[e])), iv[e]);
            const bool s = (vv[e] >= vth);
            cnt[e] += s ? 1.0f : 0.0f;
            vv[e]   = s ? vrs : vv[e];
        }
    }
    ((float4*)spikes)[idx4] = make_float4(cnt[0], cnt[1], cnt[2], cnt[3]);
}

// -------- fallback k1 (R18, verified): used when ws_size is too small -------
__global__ __launch_bounds__(256) void k1_f32chain_snn(
    const float* __restrict__ X, const float* __restrict__ W1,
    const float* __restrict__ b1,
    const void* tau_mem_p, const void* tau_syn_p,
    const void* v_thresh_p, const void* v_reset_p, const void* ts_p,
    float* __restrict__ spikes, int M, int N, int K, int f0)
{
    __shared__ float As[128][LDA];
    __shared__ float Bs[128][LDA];

    const int t  = threadIdx.x;
    const int tx = t & 15;
    const int ty = t >> 4;
    const int m0 = blockIdx.x * 128;
    const int n0 = blockIdx.y * 128;

    float c[8][8] = {};
    float p[8][8] = {};

    for (int k0 = 0; k0 < K; k0 += 32) {
        #pragma unroll
        for (int cc = 0; cc < 4; ++cc) {
            const int li  = cc * 256 + t;
            const int row = li >> 3;
            const int q   = li & 7;
            *(float4*)&As[row][q * 4] =
                *(const float4*)&X[(size_t)(m0 + row) * K + k0 + q * 4];
            *(float4*)&Bs[row][q * 4] =
                *(const float4*)&W1[(size_t)(n0 + row) * K + k0 + q * 4];
        }
        __syncthreads();
        #pragma unroll
        for (int g = 0; g < 8; ++g) {
            float4 af[8], bf[8];
            #pragma unroll
            for (int i = 0; i < 8; ++i)
                af[i] = *(const float4*)&As[ty + 16 * i][g * 4];
            #pragma unroll
            for (int j = 0; j < 8; ++j)
                bf[j] = *(const float4*)&Bs[tx + 16 * j][g * 4];
            #pragma unroll
            for (int kk = 0; kk < 4; ++kk) {
                #pragma unroll
                for (int i = 0; i < 8; ++i) {
                    const float a = ((const float*)&af[i])[kk];
                    #pragma unroll
                    for (int j = 0; j < 8; ++j)
                        p[i][j] = __builtin_fmaf(a, ((const float*)&bf[j])[kk], p[i][j]);
                }
            }
        }
        __syncthreads();
        const int ke = k0 + 32;
        if (ke == f0 || ke == K) {
            #pragma unroll
            for (int i = 0; i < 8; ++i)
                #pragma unroll
                for (int j = 0; j < 8; ++j) {
                    c[i][j] = vaddf(c[i][j], p[i][j]);
                    p[i][j] = 0.0f;
                }
        }
    }

    const float tau_m = decode_scalar(tau_mem_p, 10.0f);
    const float tau_s = decode_scalar(tau_syn_p, 5.0f);
    const float vth   = decode_scalar(v_thresh_p, 1.0f);
    const float vrs   = decode_scalar(v_reset_p, 0.0f);
    const int   ts    = decode_ts(ts_p);
    const float rs    = 1.0f / tau_s;
    const float rm    = 1.0f / tau_m;
    const float ivts  = 1.0f / (float)ts;

    #pragma unroll
    for (int j = 0; j < 8; ++j) {
        const int col    = n0 + tx + 16 * j;
        const float bias = b1[col];
        float cur[8], iv[8], vv[8], cnt[8];
        #pragma unroll
        for (int i = 0; i < 8; ++i) {
            cur[i] = vmulf(vaddf(c[i][j], bias), ivts);
            iv[i] = 0.0f; vv[i] = 0.0f; cnt[i] = 0.0f;
        }
        for (int tt = 0; tt < ts; ++tt) {
            #pragma unroll
            for (int i = 0; i < 8; ++i) {
                iv[i] = vaddf(vsubf(iv[i], vmulf(rs, iv[i])), cur[i]);
                vv[i] = vaddf(vsubf(vv[i], vmulf(rm, vv[i])), iv[i]);
                const bool s = (vv[i] >= vth);
                cnt[i] += s ? 1.0f : 0.0f;
                vv[i]   = s ? vrs : vv[i];
            }
        }
        #pragma unroll
        for (int i = 0; i < 8; ++i)
            spikes[(size_t)(m0 + ty + 16 * i) * N + col] = cnt[i];
    }
}

// -------- k2a: split-K partial GEMM (MFMA bf16-split), no bias --------------
// z selects a KC2=512 k-range; partial -> Pt[z]. 1024 blocks = 4/CU (vs the
// old full-K k2's 256 = 1/CU, which was latency-bound at ~100+ us).
__global__ __launch_bounds__(256) void k2_partial(
    const float* __restrict__ S, const float* __restrict__ W2,
    float* __restrict__ Pt,      // [4][M,N2] partials
    int M, int N2, int K2, int KC2)
{
    __shared__ __align__(16) short Sa[64 * 32];
    __shared__ __align__(16) short Bh[64 * 32];
    __shared__ __align__(16) short Bm[64 * 32];

    const int t    = threadIdx.x;
    const int l    = t & 63;
    const int w    = t >> 6;
    const int quad = l >> 4;
    const int r    = l & 15;
    const int wm   = w & 1;
    const int wn   = w >> 1;

    const int m0 = blockIdx.x * 64;
    const int n0 = blockIdx.y * 64;
    const int kz = blockIdx.z * KC2;
    float* __restrict__ outp = Pt + (size_t)blockIdx.z * M * N2;

    f32x4 acc[2][2] = {};

    for (int k0 = kz; k0 < kz + KC2; k0 += 32) {
        #pragma unroll
        for (int cc = 0; cc < 2; ++cc) {
            const int li  = cc * 256 + t;
            const int row = li >> 3;
            const int q   = li & 7;
            const float4 vs = *(const float4*)&S[(size_t)(m0 + row) * K2 + k0 + q * 4];
            *(short4*)&Sa[row * 32 + q * 4] =
                make_short4(bf16h(vs.x), bf16h(vs.y), bf16h(vs.z), bf16h(vs.w));
            const float4 vb = *(const float4*)&W2[(size_t)(n0 + row) * K2 + k0 + q * 4];
            short h[4], m_[4];
            split2(vb.x, h[0], m_[0]); split2(vb.y, h[1], m_[1]);
            split2(vb.z, h[2], m_[2]); split2(vb.w, h[3], m_[3]);
            *(short4*)&Bh[row * 32 + q * 4] = make_short4(h[0], h[1], h[2], h[3]);
            *(short4*)&Bm[row * 32 + q * 4] = make_short4(m_[0], m_[1], m_[2], m_[3]);
        }
        __syncthreads();

        bf16x8 af[2], bh[2], bm[2];
        #pragma unroll
        for (int i = 0; i < 2; ++i) {
            af[i] = *(const bf16x8*)&Sa[(wm * 32 + i * 16 + r) * 32 + quad * 8];
            bh[i] = *(const bf16x8*)&Bh[(wn * 32 + i * 16 + r) * 32 + quad * 8];
            bm[i] = *(const bf16x8*)&Bm[(wn * 32 + i * 16 + r) * 32 + quad * 8];
        }
        #pragma unroll
        for (int i = 0; i < 2; ++i)
            #pragma unroll
            for (int j = 0; j < 2; ++j) {
                acc[i][j] = __builtin_amdgcn_mfma_f32_16x16x32_bf16(af[i], bh[j], acc[i][j], 0, 0, 0);
                acc[i][j] = __builtin_amdgcn_mfma_f32_16x16x32_bf16(af[i], bm[j], acc[i][j], 0, 0, 0);
            }
        __syncthreads();
    }

    #pragma unroll
    for (int j = 0; j < 2; ++j) {
        const int col = n0 + wn * 32 + j * 16 + r;
        #pragma unroll
        for (int i = 0; i < 2; ++i) {
            const int rowb = m0 + wm * 32 + i * 16 + quad * 4;
            #pragma unroll
            for (int e = 0; e < 4; ++e)
                outp[(size_t)(rowb + e) * N2 + col] = acc[i][j][e];
        }
    }
}

// -------- k2b: out = p0+p1+p2+p3 + b2 ---------------------------------------
__global__ __launch_bounds__(256) void k2_combine(
    const float* __restrict__ Pt, const float* __restrict__ b2,
    float* __restrict__ out, int N2, int total4, size_t stride4)
{
    const int idx4 = blockIdx.x * 256 + threadIdx.x;
    if (idx4 >= total4) return;
    float4 s = ((const float4*)Pt)[idx4];
    #pragma unroll
    for (int z = 1; z < 4; ++z) {
        const float4 v = ((const float4*)Pt)[stride4 * z + idx4];
        s.x += v.x; s.y += v.y; s.z += v.z; s.w += v.w;
    }
    const float4 bb = *(const float4*)&b2[(idx4 * 4) % N2];
    s.x += bb.x; s.y += bb.y; s.z += bb.z; s.w += bb.w;
    ((float4*)out)[idx4] = s;
}

// -------- fallback k2 (verified R4-R19): full-K, bias fused -----------------
__global__ __launch_bounds__(256) void k2_gemm(
    const float* __restrict__ S, const float* __restrict__ W2,
    const float* __restrict__ b2, float* __restrict__ out,
    int M, int N2, int K2)
{
    __shared__ __align__(16) short Sa[64 * 32];
    __shared__ __align__(16) short Bh[64 * 32];
    __shared__ __align__(16) short Bm[64 * 32];

    const int t    = threadIdx.x;
    const int l    = t & 63;
    const int w    = t >> 6;
    const int quad = l >> 4;
    const int r    = l & 15;
    const int wm   = w & 1;
    const int wn   = w >> 1;

    const int m0 = blockIdx.x * 64;
    const int n0 = blockIdx.y * 64;

    f32x4 acc[2][2] = {};

    for (int k0 = 0; k0 < K2; k0 += 32) {
        #pragma unroll
        for (int cc = 0; cc < 2; ++cc) {
            const int li  = cc * 256 + t;
            const int row = li >> 3;
            const int q   = li & 7;
            const float4 vs = *(const float4*)&S[(size_t)(m0 + row) * K2 + k0 + q * 4];
            *(short4*)&Sa[row * 32 + q * 4] =
                make_short4(bf16h(vs.x), bf16h(vs.y), bf16h(vs.z), bf16h(vs.w));
            const float4 vb = *(const float4*)&W2[(size_t)(n0 + row) * K2 + k0 + q * 4];
            short h[4], m_[4];
            split2(vb.x, h[0], m_[0]); split2(vb.y, h[1], m_[1]);
            split2(vb.z, h[2], m_[2]); split2(vb.w, h[3], m_[3]);
            *(short4*)&Bh[row * 32 + q * 4] = make_short4(h[0], h[1], h[2], h[3]);
            *(short4*)&Bm[row * 32 + q * 4] = make_short4(m_[0], m_[1], m_[2], m_[3]);
        }
        __syncthreads();

        bf16x8 af[2], bh[2], bm[2];
        #pragma unroll
        for (int i = 0; i < 2; ++i) {
            af[i] = *(const bf16x8*)&Sa[(wm * 32 + i * 16 + r) * 32 + quad * 8];
            bh[i] = *(const bf16x8*)&Bh[(wn * 32 + i * 16 + r) * 32 + quad * 8];
            bm[i] = *(const bf16x8*)&Bm[(wn * 32 + i * 16 + r) * 32 + quad * 8];
        }
        #pragma unroll
        for (int i = 0; i < 2; ++i)
            #pragma unroll
            for (int j = 0; j < 2; ++j) {
                acc[i][j] = __builtin_amdgcn_mfma_f32_16x16x32_bf16(af[i], bh[j], acc[i][j], 0, 0, 0);
                acc[i][j] = __builtin_amdgcn_mfma_f32_16x16x32_bf16(af[i], bm[j], acc[i][j], 0, 0, 0);
            }
        __syncthreads();
    }

    #pragma unroll
    for (int j = 0; j < 2; ++j) {
        const int col = n0 + wn * 32 + j * 16 + r;
        const float bias = b2[col];
        #pragma unroll
        for (int i = 0; i < 2; ++i) {
            const int rowb = m0 + wm * 32 + i * 16 + quad * 4;
            #pragma unroll
            for (int e = 0; e < 4; ++e)
                out[(size_t)(rowb + e) * N2 + col] = __fadd_rn(acc[i][j][e], bias);
        }
    }
}

extern "C" void kernel_launch(void* const* d_in, const int* in_sizes, int n_in,
                              void* d_out, int out_size, void* d_ws, size_t ws_size,
                              hipStream_t stream) {
    (void)n_in; (void)out_size;

    const float* X  = (const float*)d_in[0];
    const float* W1 = (const float*)d_in[1];
    const float* b1 = (const float*)d_in[2];
    const float* W2 = (const float*)d_in[3];
    const float* b2 = (const float*)d_in[4];
    const void* tau_mem = d_in[5];
    const void* tau_syn = d_in[6];
    const void* vth     = d_in[7];
    const void* vrs     = d_in[8];
    const void* ts      = d_in[11];

    const int H   = in_sizes[2];             // 2048
    const int IN  = in_sizes[1] / H;         // 1024
    const int OUT = in_sizes[4];             // 256
    const int B   = in_sizes[0] / IN;        // 4096

    float* out    = (float*)d_out;           // [B, OUT] fp32
    float* spikes = out + (size_t)B * OUT;   // [B, H]  fp32

    const int KC = 512;                      // VERIFIED: AOCL-BLIS zen KC
    const size_t panel_bytes = (size_t)B * H * sizeof(float);
    const bool ws_ok = (IN == 2 * KC) && (ws_size >= panel_bytes) &&
                       ((uintptr_t)d_ws % 16 == 0);

    if (ws_ok) {
        float* P1 = (float*)d_ws;
        dim3 g1(B / 128, H / 128, 2);
        k1_panel_gemm<<<g1, 256, 0, stream>>>(X, W1, spikes, P1, B, H, IN, KC);

        const int total4 = (B * H) / 4;
        k1_combine_scan<<<(total4 + 255) / 256, 256, 0, stream>>>(
            spikes, P1, b1, tau_mem, tau_syn, vth, vrs, ts, spikes, H, total4);
    } else {
        dim3 g1(B / 128, H / 128);
        k1_f32chain_snn<<<g1, 256, 0, stream>>>(X, W1, b1, tau_mem, tau_syn, vth, vrs, ts,
                                                spikes, B, H, IN, KC);
    }

    // k2: split-K z=4 partials into d_ws (free after combine_scan; 16 MB),
    // then tiny combine. Falls back to full-K k2 if ws not usable.
    const int KC2 = 512;
    const size_t k2_part_bytes = 4 * (size_t)B * OUT * sizeof(float);
    if (ws_ok && H == 4 * KC2 && ws_size >= k2_part_bytes) {
        float* Pt = (float*)d_ws;
        dim3 g2(B / 64, OUT / 64, 4);
        k2_partial<<<g2, 256, 0, stream>>>(spikes, W2, Pt, B, OUT, H, KC2);
        const int total4 = (B * OUT) / 4;
        k2_combine<<<(total4 + 255) / 256, 256, 0, stream>>>(
            Pt, b2, out, OUT, total4, (size_t)B * OUT / 4);
    } else {
        dim3 g2(B / 64, OUT / 64);
        k2_gemm<<<g2, 256, 0, stream>>>(spikes, W2, b2, out, B, OUT, H);
    }
}